// Round 6
// baseline (10338.598 us; speedup 1.0000x reference)
//
#include <hip/hip_runtime.h>
#include <math.h>

// ---------------- problem constants ----------------
#define EPSP 5.0f
#define BNEPS 1e-5f
constexpr int B_  = 64;    // batch
constexpr int T_  = 768;   // timesteps in
constexpr int D_  = 128;   // input feature
constexpr int E_  = 64;    // embedding (conv out channels)
constexpr int H_  = 128;   // hidden
constexpr int FH_ = 512;   // 4*H
constexpr int TC_ = 256;   // conv output steps
constexpr int O_  = 10;    // output classes

// ---------------- workspace layout (floats) ----------------
constexpr size_t EMB_OFF = 0;                                   // B*TC*E   [b][tc][e]
constexpr size_t SUM_OFF = EMB_OFF + (size_t)B_ * TC_ * E_;     // 128  (sum[64], ssq[64])
constexpr size_t SCL_OFF = SUM_OFF + 128;                       // 128  (scale[64], shift[64])
constexpr size_t WT_OFF  = SCL_OFF + 128;                       // 24576: w_ih transposed [gate(i,f,g)][e][j]
constexpr size_t WIH_OFF = WT_OFF + (size_t)FH_ * H_;           // 32768  packed [e4][j][4] (zx_kernel)
constexpr size_t CWT_OFF = WIH_OFF + (size_t)FH_ * E_;          // 24576  [k][d][e]
constexpr size_t ZX_OFF  = CWT_OFF + (size_t)E_ * D_ * 3;       // B*TC*FH [b][t][j]
constexpr size_t WS_FLOATS = ZX_OFF + (size_t)B_ * TC_ * FH_;

typedef __bf16 bf16x8 __attribute__((ext_vector_type(8)));
typedef __bf16 bf16x2 __attribute__((ext_vector_type(2)));
typedef float  floatx4 __attribute__((ext_vector_type(4)));

__device__ inline float fast_rcp(float x) {
#if __has_builtin(__builtin_amdgcn_rcpf)
  return __builtin_amdgcn_rcpf(x);
#else
  return 1.0f / x;
#endif
}
__device__ inline float frsq(float x) {
#if __has_builtin(__builtin_amdgcn_rsqf)
  return __builtin_amdgcn_rsqf(x);
#else
  return rsqrtf(x);
#endif
}
__device__ inline float fexp2(float x) {
#if __has_builtin(__builtin_amdgcn_exp2f)
  return __builtin_amdgcn_exp2f(x);
#else
  return exp2f(x);
#endif
}
__device__ inline float rl(float v, int lane) {
  return __int_as_float(__builtin_amdgcn_readlane(__float_as_int(v), lane));
}
#define LOG2E 1.4426950408889634f
__device__ inline float fsigmoid(float x) {
  return fast_rcp(1.f + fexp2(-LOG2E * x));
}
__device__ inline float ftanh(float x) {
  return 1.f - 2.f * fast_rcp(1.f + fexp2(2.f * LOG2E * x));
}

// ---------------- prep: weight repack + zero BN sums ----------------
__global__ void prep_kernel(const float* __restrict__ conv_w,
                            const float* __restrict__ w_ih,
                            float* __restrict__ ws) {
  int gid = blockIdx.x * blockDim.x + threadIdx.x;
  int nthr = gridDim.x * blockDim.x;
  for (int i = gid; i < 128; i += nthr) ws[SUM_OFF + i] = 0.f;
  // w_ih [512][64] -> packed [16][512][4]  (zx_kernel)
  for (int s = gid; s < FH_ * E_; s += nthr) {
    int j = s >> 6, e = s & 63;
    ws[WIH_OFF + ((size_t)(e >> 2) * FH_ + j) * 4 + (e & 3)] = w_ih[s];
  }
  // w_ih gates i,f,g transposed: Wt[g][e][j] = w_ih[(g*128+j)*64+e]  (scan G-build)
  for (int s = gid; s < 3 * H_ * E_ * 2; s += nthr) {   // 3*64*128 = 24576
    int g = s >> 13; int r = s & 8191; int e = r >> 7; int j = r & 127;
    ws[WT_OFF + s] = w_ih[((size_t)(g * 128 + j)) * 64 + e];
  }
  // conv_w [e][d][k] -> [k][d][e]
  for (int s = gid; s < E_ * D_ * 3; s += nthr) {
    int e = s / 384; int r = s - e * 384; int d = r / 3; int k = r - d * 3;
    ws[CWT_OFF + ((size_t)k * D_ + d) * E_ + e] = conv_w[s];
  }
}

// ---------------- conv + L2-normalize + BN partial sums ----------------
__global__ __launch_bounds__(256) void conv_bn_kernel(const float* __restrict__ inputs,
                                                      const float* __restrict__ conv_b,
                                                      float* __restrict__ ws) {
  __shared__ float xin[48 * 129];
  __shared__ float rnorm[48];
  __shared__ float cwc[3 * 16 * 64];
  __shared__ float bnr1[256], bnr2[256];
  int tid = threadIdx.x;
  int bb = blockIdx.x >> 4, tcg = blockIdx.x & 15;
  const float* inp = inputs + ((size_t)bb * T_ + (size_t)tcg * 48) * D_;
  for (int idx = tid; idx < 48 * 128; idx += 256) {
    int r = idx >> 7, d = idx & 127;
    xin[r * 129 + d] = inp[idx];
  }
  __syncthreads();
  if (tid < 48) {
    float ss = 0.f;
    for (int d = 0; d < 128; ++d) { float v = xin[tid * 129 + d]; ss += v * v; }
    rnorm[tid] = 1.0f / fmaxf(sqrtf(ss), 1e-12f);
  }
  __syncthreads();
  for (int idx = tid; idx < 48 * 128; idx += 256) {
    int r = idx >> 7, d = idx & 127;
    xin[r * 129 + d] *= rnorm[r];
  }
  int e = tid & 63, tg = tid >> 6;
  float cb = conv_b[e];
  float acc[4];
#pragma unroll
  for (int q = 0; q < 4; ++q) acc[q] = cb;
  for (int ch = 0; ch < 8; ++ch) {
    __syncthreads();
    for (int idx = tid; idx < 3072; idx += 256) {
      int k = idx >> 10; int i2 = idx & 1023; int dd = i2 >> 6; int e2 = i2 & 63;
      cwc[idx] = ws[CWT_OFF + ((size_t)k * D_ + ch * 16 + dd) * E_ + e2];
    }
    __syncthreads();
    for (int dd = 0; dd < 16; ++dd) {
      int dcol = ch * 16 + dd;
#pragma unroll
      for (int k = 0; k < 3; ++k) {
        float w = cwc[(k * 16 + dd) * 64 + e];
#pragma unroll
        for (int q = 0; q < 4; ++q) {
          int tcl = tg * 4 + q;
          acc[q] += w * xin[(3 * tcl + k) * 129 + dcol];
        }
      }
    }
  }
  float ps = 0.f, pss = 0.f;
#pragma unroll
  for (int q = 0; q < 4; ++q) {
    int tcl = tg * 4 + q;
    ws[EMB_OFF + ((size_t)bb * TC_ + tcg * 16 + tcl) * E_ + e] = acc[q];
    ps += acc[q]; pss += acc[q] * acc[q];
  }
  bnr1[tg * 64 + e] = ps;
  bnr2[tg * 64 + e] = pss;
  __syncthreads();
  if (tid < 64) {
    float s1 = bnr1[tid] + bnr1[64 + tid] + bnr1[128 + tid] + bnr1[192 + tid];
    float s2 = bnr2[tid] + bnr2[64 + tid] + bnr2[128 + tid] + bnr2[192 + tid];
    atomicAdd(&ws[SUM_OFF + tid], s1);
    atomicAdd(&ws[SUM_OFF + 64 + tid], s2);
  }
}

// ---------------- BN finalize ----------------
__global__ void bn_finalize_kernel(const float* __restrict__ gamma,
                                   const float* __restrict__ beta,
                                   float* __restrict__ ws) {
  int e = threadIdx.x;
  if (e < 64) {
    const float n = (float)(B_ * TC_);
    float mean = ws[SUM_OFF + e] / n;
    float var = ws[SUM_OFF + 64 + e] / n - mean * mean;
    float sc = gamma[e] * rsqrtf(var + BNEPS);
    ws[SCL_OFF + e] = sc;
    ws[SCL_OFF + 64 + e] = beta[e] - mean * sc;
  }
}

// ---------------- z_x = relu(bn(emb)) @ w_ih^T + b_ih + b_hh ----------------
__global__ __launch_bounds__(256) void zx_kernel(const float* __restrict__ b_ih,
                                                 const float* __restrict__ b_hh,
                                                 float* __restrict__ ws) {
  __shared__ __align__(16) float actT[16 * 64];
  int tid = threadIdx.x;
  int bb = blockIdx.x >> 4, tg2 = blockIdx.x & 15;
  for (int idx = tid; idx < 1024; idx += 256) {
    int tl = idx >> 6, e2 = idx & 63;
    float v = ws[EMB_OFF + ((size_t)bb * TC_ + tg2 * 16 + tl) * E_ + e2];
    actT[idx] = fmaxf(v * ws[SCL_OFF + e2] + ws[SCL_OFF + 64 + e2], 0.f);
  }
  __syncthreads();
  int j0 = tid, j1 = tid + 256;
  float acc0[16], acc1[16];
  float bias0 = b_ih[j0] + b_hh[j0];
  float bias1 = b_ih[j1] + b_hh[j1];
#pragma unroll
  for (int tl = 0; tl < 16; ++tl) { acc0[tl] = bias0; acc1[tl] = bias1; }
  const float* wp = ws + WIH_OFF;
  for (int e4 = 0; e4 < 16; ++e4) {
    float4 w0 = *(const float4*)(wp + ((size_t)e4 * FH_ + j0) * 4);
    float4 w1 = *(const float4*)(wp + ((size_t)e4 * FH_ + j1) * 4);
#pragma unroll
    for (int tl = 0; tl < 16; ++tl) {
      float4 a4 = *(const float4*)(actT + tl * 64 + e4 * 4);
      acc0[tl] += w0.x * a4.x + w0.y * a4.y + w0.z * a4.z + w0.w * a4.w;
      acc1[tl] += w1.x * a4.x + w1.y * a4.y + w1.z * a4.z + w1.w * a4.w;
    }
  }
#pragma unroll
  for (int tl = 0; tl < 16; ++tl) {
    size_t base = ZX_OFF + ((size_t)bb * TC_ + tg2 * 16 + tl) * FH_;
    ws[base + j0] = acc0[tl];
    ws[base + j1] = acc1[tl];
  }
}

// ---------------- Gram tile helper: 5 C tiles (4 M cols + y col) ----------------
__device__ inline void gram_do5(int rt, int lane,
                                const __bf16* GtHi, const __bf16* GtLo,
                                float* M_b, float* y_b) {
  int m = lane & 15, q = lane >> 4;
  floatx4 C[5];
#pragma unroll
  for (int ci = 0; ci < 5; ++ci) C[ci] = (floatx4){0.f, 0.f, 0.f, 0.f};
#pragma unroll
  for (int p = 0; p < 3; ++p) {
    const __bf16* Aa = (p < 2) ? GtHi : GtLo;
    const __bf16* Ba = (p == 1) ? GtLo : GtHi;
    bf16x8 Af[4];
#pragma unroll
    for (int kt = 0; kt < 4; ++kt)
      Af[kt] = *(const bf16x8*)(Aa + (rt * 16 + m) * 136 + kt * 32 + q * 8);
#pragma unroll
    for (int ci = 0; ci < 5; ++ci) {
#pragma unroll
      for (int kt = 0; kt < 4; ++kt) {
        bf16x8 Bf = *(const bf16x8*)(Ba + (ci * 16 + m) * 136 + kt * 32 + q * 8);
        C[ci] = __builtin_amdgcn_mfma_f32_16x16x32_bf16(Af[kt], Bf, C[ci], 0, 0, 0);
      }
    }
  }
#pragma unroll
  for (int ci = 0; ci < 5; ++ci) {
#pragma unroll
    for (int reg = 0; reg < 4; ++reg) {
      int grow = rt * 16 + q * 4 + reg;
      if (ci < 4) {
        int gcol = ci * 16 + m;
        M_b[grow * 65 + gcol] = EPSP * C[ci][reg] + ((grow == gcol) ? 1.f : 0.f);
      } else if (m == 0) {
        y_b[grow] = C[ci][reg];   // y = G^T s
      }
    }
  }
}

// consume one float4 of w_hh against 4 broadcast h values, for BOTH batches
#define FMA4B(W, H0, H1, BOFF)                      \
  acc0 = fmaf(rl(H0, (BOFF) + 0), (W).x, acc0);     \
  acc1 = fmaf(rl(H1, (BOFF) + 0), (W).x, acc1);     \
  acc0 = fmaf(rl(H0, (BOFF) + 1), (W).y, acc0);     \
  acc1 = fmaf(rl(H1, (BOFF) + 1), (W).y, acc1);     \
  acc0 = fmaf(rl(H0, (BOFF) + 2), (W).z, acc0);     \
  acc1 = fmaf(rl(H1, (BOFF) + 2), (W).z, acc1);     \
  acc0 = fmaf(rl(H0, (BOFF) + 3), (W).w, acc0);     \
  acc1 = fmaf(rl(H1, (BOFF) + 3), (W).w, acc1);

// ---------------- the sequential ProxLSTM scan: TWO batches per block ----------------
// Rationale: serial chains are latency-bound (76% VALU idle on active CUs). Two
// independent batches per block share weights (halved L2 traffic per batch), share
// barriers, and interleave their serial Cholesky/solve chains on the SIMDs.
constexpr int GTS = 80 * 136;   // per-batch Gt tile (rows 64=s, 65-79=0)
constexpr int BXS = 16 * 72;
constexpr int MSS = 64 * 65;
__global__ __launch_bounds__(512) void scan_kernel(const float* __restrict__ w_hh,
                                                   const float* __restrict__ lin_w,
                                                   const float* __restrict__ lin_b,
                                                   const float* __restrict__ ws,
                                                   float* __restrict__ out) {
  __shared__ __align__(16) __bf16 GtHi[2 * GTS], GtLo[2 * GTS];
  __shared__ __align__(16) __bf16 BxHi[2 * BXS], BxLo[2 * BXS];
  __shared__ float M_s[2 * MSS];
  __shared__ float Lp_s[2 * 1024];
  __shared__ float z_s[2 * 512];
  __shared__ float s_s[2 * 128], o_s[2 * 128], a1_s[2 * 128], a2_s[2 * 128], a3_s[2 * 128];
  __shared__ __align__(16) float c_s[2 * 128], h_s[2 * 128];
  __shared__ float y_s[2 * 64];

  int tid = threadIdx.x;
  int bb = blockIdx.x;            // 32 blocks; batches 2bb, 2bb+1
  int lane = tid & 63;
  int wv = tid >> 6;

  int hg = tid >> 5, ep = tid & 31;      // G-build mapping: 16 row-groups x 32 col-groups
  int h0 = hg * 8, e0 = ep * 2;

  const float4* wr = (const float4*)(w_hh + (size_t)tid * H_);   // this thread's z-row
  const float*  wt = ws + WT_OFF;

  // ---- zero-init LDS constants ----
  for (int i = tid; i < 15 * 136; i += 512) {
    GtHi[65 * 136 + i] = (__bf16)0.f; GtLo[65 * 136 + i] = (__bf16)0.f;
    GtHi[GTS + 65 * 136 + i] = (__bf16)0.f; GtLo[GTS + 65 * 136 + i] = (__bf16)0.f;
  }
  for (int i = tid; i < 15 * 72; i += 512) {
    BxHi[72 + i] = (__bf16)0.f; BxLo[72 + i] = (__bf16)0.f;
    BxHi[BXS + 72 + i] = (__bf16)0.f; BxLo[BXS + 72 + i] = (__bf16)0.f;
  }
  if (tid < 256) { c_s[tid] = 0.f; h_s[tid] = 0.f; }   // [2][128] flat

  // zx stream: threads 0..255 own (bq = tid>>7, h = tid&127)
  const float* zxq = nullptr;
  float zx0 = 0.f, zx1 = 0.f, zx2 = 0.f, zx3 = 0.f;
  if (tid < 256) {
    int bq = tid >> 7, h = tid & 127;
    zxq = ws + ZX_OFF + (size_t)(2 * bb + bq) * TC_ * FH_;
    zx0 = zxq[h]; zx1 = zxq[128 + h]; zx2 = zxq[256 + h]; zx3 = zxq[384 + h];
  }
  float dinv = 1.f;   // factor waves: 1/L[lane][lane]
  float4 tv[12];      // G-build weights (shared across batches)
  __syncthreads();

  for (int t = 0; t < TC_; ++t) {
    // ---- A: z[bq][tid] = w_hh[tid,:] . h[bq]  (one weight load, two batches) ----
    {
      float hA0 = h_s[lane],       hB0 = h_s[64 + lane];
      float hA1 = h_s[128 + lane], hB1 = h_s[192 + lane];
      float4 cb0[8], cb1[8];
#pragma unroll
      for (int k = 0; k < 8; ++k) cb0[k] = wr[k];
#pragma unroll
      for (int k = 0; k < 8; ++k) cb1[k] = wr[8 + k];
      float acc0 = 0.f, acc1 = 0.f;
#pragma unroll
      for (int k = 0; k < 8; ++k) { FMA4B(cb0[k], hA0, hA1, 4 * k) }
#pragma unroll
      for (int k = 0; k < 8; ++k) cb0[k] = wr[16 + k];
#pragma unroll
      for (int k = 0; k < 8; ++k) { FMA4B(cb1[k], hA0, hA1, 32 + 4 * k) }
#pragma unroll
      for (int k = 0; k < 8; ++k) cb1[k] = wr[24 + k];
#pragma unroll
      for (int k = 0; k < 8; ++k) { FMA4B(cb0[k], hB0, hB1, 4 * k) }
#pragma unroll
      for (int k = 0; k < 8; ++k) { FMA4B(cb1[k], hB0, hB1, 32 + 4 * k) }
      z_s[tid] = acc0;
      z_s[512 + tid] = acc1;
      // issue G-build weight stream (drains at this phase's barrier)
#pragma unroll
      for (int g = 0; g < 3; ++g)
#pragma unroll
        for (int e = 0; e < 2; ++e)
#pragma unroll
          for (int hf = 0; hf < 2; ++hf)
            tv[g * 4 + e * 2 + hf] =
                *(const float4*)(wt + (size_t)g * 8192 + (size_t)(e0 + e) * 128 + h0 + hf * 4);
    }
    __syncthreads();
    // ---- stage 1 (tid<256): gates for (bq, h) ----
    if (tid < 256) {
      int bq = tid >> 7, h = tid & 127;
      const float* zb = z_s + bq * 512;
      float zi = zb[h] + zx0, zf = zb[128 + h] + zx1, zg = zb[256 + h] + zx2, zo = zb[384 + h] + zx3;
      float c = c_s[bq * 128 + h];
      float ig = fsigmoid(zi);
      float fg = fsigmoid(zf);
      float gg = ftanh(zg);
      float s = fg * c + ig * gg;
      s_s[bq * 128 + h] = s;
      o_s[bq * 128 + h] = fsigmoid(zo);
      a1_s[bq * 128 + h] = ig * (1.f - ig) * gg;
      a2_s[bq * 128 + h] = fg * (1.f - fg) * c;
      a3_s[bq * 128 + h] = ig * (1.f - gg * gg);
      __bf16 sh = (__bf16)s;
      GtHi[bq * GTS + 64 * 136 + h] = sh;
      GtLo[bq * GTS + 64 * 136 + h] = (__bf16)(s - (float)sh);
      if (t + 1 < TC_) {
        const float* zn = zxq + (size_t)(t + 1) * FH_;
        zx0 = zn[h]; zx1 = zn[128 + h]; zx2 = zn[256 + h]; zx3 = zn[384 + h];
      }
    }
    __syncthreads();
    // ---- stage 2 (all): G build for BOTH batches from shared tv ----
    {
      const float* tvf = (const float*)tv;   // tvf[g*16 + e*8 + jj]
#pragma unroll
      for (int bq = 0; bq < 2; ++bq) {
        const float* a1p = a1_s + bq * 128 + h0;
        const float* a2p = a2_s + bq * 128 + h0;
        const float* a3p = a3_s + bq * 128 + h0;
        float A1[8], A2[8], A3[8];
        {
          float4 v0 = *(const float4*)(a1p); float4 v1 = *(const float4*)(a1p + 4);
          A1[0] = v0.x; A1[1] = v0.y; A1[2] = v0.z; A1[3] = v0.w;
          A1[4] = v1.x; A1[5] = v1.y; A1[6] = v1.z; A1[7] = v1.w;
          float4 v2 = *(const float4*)(a2p); float4 v3 = *(const float4*)(a2p + 4);
          A2[0] = v2.x; A2[1] = v2.y; A2[2] = v2.z; A2[3] = v2.w;
          A2[4] = v3.x; A2[5] = v3.y; A2[6] = v3.z; A2[7] = v3.w;
          float4 v4 = *(const float4*)(a3p); float4 v5 = *(const float4*)(a3p + 4);
          A3[0] = v4.x; A3[1] = v4.y; A3[2] = v4.z; A3[3] = v4.w;
          A3[4] = v5.x; A3[5] = v5.y; A3[6] = v5.z; A3[7] = v5.w;
        }
        __bf16 ghi[2][8], glo[2][8];
#pragma unroll
        for (int e = 0; e < 2; ++e) {
#pragma unroll
          for (int jj = 0; jj < 8; ++jj) {
            float gv = A1[jj] * tvf[e * 8 + jj] + A2[jj] * tvf[16 + e * 8 + jj] + A3[jj] * tvf[32 + e * 8 + jj];
            __bf16 hi = (__bf16)gv;
            ghi[e][jj] = hi;
            glo[e][jj] = (__bf16)(gv - (float)hi);
          }
        }
#pragma unroll
        for (int e = 0; e < 2; ++e) {
          bf16x8 vh, vl;
#pragma unroll
          for (int jj = 0; jj < 8; ++jj) { vh[jj] = ghi[e][jj]; vl[jj] = glo[e][jj]; }
          *(bf16x8*)(&GtHi[bq * GTS + (e0 + e) * 136 + h0]) = vh;
          *(bf16x8*)(&GtLo[bq * GTS + (e0 + e) * 136 + h0]) = vl;
        }
      }
    }
    __syncthreads();
    // ---- Gram via MFMA: per batch 4 waves, 5 col-tiles each ----
    {
      int bq = wv >> 2, w = wv & 3;
      gram_do5(w, lane, GtHi + bq * GTS, GtLo + bq * GTS, M_s + bq * MSS, y_s + bq * 64);
    }
    __syncthreads();
    // ---- D: Cholesky per batch (factor: waves 0 & 4; trailing: 4 waves each) ----
#pragma unroll 1
    for (int pan = 0; pan < 4; ++pan) {
      int j0 = pan * 16;
      if ((wv & 3) == 0) {
        int bq = wv >> 2;
        float* M = M_s + bq * MSS;
        float* Lp = Lp_s + bq * 1024;
        float p[16];
#pragma unroll
        for (int jj = 0; jj < 16; ++jj) p[jj] = M[lane * 65 + j0 + jj];
#pragma unroll
        for (int jj = 0; jj < 16; ++jj) {
          float d  = rl(p[jj], j0 + jj);
          float rs = frsq(d);
          p[jj] *= rs;                         // diag lane: d*rs = sqrt(d)
          dinv = (lane == j0 + jj) ? rs : dinv;
#pragma unroll
          for (int kk = jj + 1; kk < 16; ++kk) {
            float l = rl(p[jj], j0 + kk);
            p[kk] -= p[jj] * l;
          }
        }
#pragma unroll
        for (int jj = 0; jj < 16; ++jj) {
          M[lane * 65 + j0 + jj] = p[jj];
          Lp[jj * 64 + lane] = p[jj];
        }
        if (pan == 3) {
          float r = y_s[bq * 64 + lane];
          // forward: L y' = y
#pragma unroll 16
          for (int i = 0; i < 64; ++i) {
            float Lri = M[lane * 65 + i];
            float vv  = rl(r, i) * rl(dinv, i);
            float upd = r - Lri * vv;
            r = (lane == i) ? vv : ((lane > i) ? upd : r);
          }
          // backward: L^T x = y'
#pragma unroll 16
          for (int i = 63; i >= 0; --i) {
            float Lil = M[i * 65 + lane];
            float vv  = rl(r, i) * rl(dinv, i);
            float upd = r - Lil * vv;
            r = (lane == i) ? vv : ((lane < i) ? upd : r);
          }
          __bf16 xh = (__bf16)r;
          BxHi[bq * BXS + lane] = xh;
          BxLo[bq * BXS + lane] = (__bf16)(r - (float)xh);
        }
      }
      __syncthreads();
      if (pan < 3) {
        int bq = wv >> 2, w = wv & 3;
        float* M = M_s + bq * MSS;
        float* Lp = Lp_s + bq * 1024;
        float Lrow[16];
#pragma unroll
        for (int jj = 0; jj < 16; ++jj) Lrow[jj] = Lp[jj * 64 + lane];
        for (int k = j0 + 16 + w; k < 64; k += 4) {
          float acc = M[lane * 65 + k];
#pragma unroll
          for (int jj = 0; jj < 16; ++jj) acc -= Lrow[jj] * Lp[jj * 64 + k];
          M[lane * 65 + k] = acc;
        }
        __syncthreads();
      }
    }
    // ---- E: u = G x via MFMA (A-frags from Gt, strided); c,h update ----
    {
      int bq = wv >> 2, w = wv & 3;
      int m = lane & 15, q = lane >> 4;
      const __bf16* GH = GtHi + bq * GTS;
      const __bf16* GL = GtLo + bq * GTS;
#pragma unroll
      for (int ti = 0; ti < 2; ++ti) {
        int T = w * 2 + ti;
        bf16x8 Ahi[2], Alo[2];
#pragma unroll
        for (int kt = 0; kt < 2; ++kt) {
#pragma unroll
          for (int j = 0; j < 8; ++j) {
            int e = kt * 32 + q * 8 + j;
            Ahi[kt][j] = GH[e * 136 + T * 16 + m];
            Alo[kt][j] = GL[e * 136 + T * 16 + m];
          }
        }
        floatx4 C = (floatx4){0.f, 0.f, 0.f, 0.f};
#pragma unroll
        for (int p = 0; p < 3; ++p) {
          const bf16x8* Ap = (p < 2) ? Ahi : Alo;
          const __bf16* Ba = (p == 1) ? (BxLo + bq * BXS) : (BxHi + bq * BXS);
#pragma unroll
          for (int kt = 0; kt < 2; ++kt) {
            bf16x8 Bf = *(const bf16x8*)(Ba + m * 72 + kt * 32 + q * 8);
            C = __builtin_amdgcn_mfma_f32_16x16x32_bf16(Ap[kt], Bf, C, 0, 0, 0);
          }
        }
        if (m == 0) {
#pragma unroll
          for (int reg = 0; reg < 4; ++reg) {
            int grow = T * 16 + q * 4 + reg;
            float u  = C[reg];
            float cn = s_s[bq * 128 + grow] - EPSP * u;
            float hn = o_s[bq * 128 + grow] * ftanh(cn);
            c_s[bq * 128 + grow] = cn;
            h_s[bq * 128 + grow] = hn;
          }
        }
      }
    }
    __syncthreads();
  }
  // ---- head: 2 batches x 10 outputs ----
  if (tid < 2 * O_) {
    int bq = (tid >= O_) ? 1 : 0;
    int j = tid - bq * O_;
    float acc = lin_b[j];
    for (int hh2 = 0; hh2 < 128; ++hh2) acc += h_s[bq * 128 + hh2] * lin_w[j * 128 + hh2];
    out[(size_t)(2 * bb + bq) * O_ + j] = acc;
  }
}

// ---------------- launch ----------------
extern "C" void kernel_launch(void* const* d_in, const int* in_sizes, int n_in,
                              void* d_out, int out_size, void* d_ws, size_t ws_size,
                              hipStream_t stream) {
  (void)in_sizes; (void)n_in; (void)out_size;
  const float* inputs  = (const float*)d_in[0];
  const float* conv_w  = (const float*)d_in[2];
  const float* conv_b  = (const float*)d_in[3];
  const float* gamma   = (const float*)d_in[4];
  const float* beta    = (const float*)d_in[5];
  const float* w_ih    = (const float*)d_in[6];
  const float* w_hh    = (const float*)d_in[7];
  const float* b_ih    = (const float*)d_in[8];
  const float* b_hh    = (const float*)d_in[9];
  const float* lin_w   = (const float*)d_in[10];
  const float* lin_b   = (const float*)d_in[11];
  float* out = (float*)d_out;
  float* ws  = (float*)d_ws;

  if (ws_size < WS_FLOATS * sizeof(float)) return;

  hipLaunchKernelGGL(prep_kernel, dim3(192), dim3(256), 0, stream, conv_w, w_ih, ws);
  hipLaunchKernelGGL(conv_bn_kernel, dim3(1024), dim3(256), 0, stream, inputs, conv_b, ws);
  hipLaunchKernelGGL(bn_finalize_kernel, dim3(1), dim3(64), 0, stream, gamma, beta, ws);
  hipLaunchKernelGGL(zx_kernel, dim3(1024), dim3(256), 0, stream, b_ih, b_hh, ws);
  hipLaunchKernelGGL(scan_kernel, dim3(32), dim3(512), 0, stream, w_hh, lin_w, lin_b, ws, out);
}

// Round 7
// 8259.518 us; speedup vs baseline: 1.2517x; 1.2517x over previous
//
#include <hip/hip_runtime.h>
#include <math.h>

// ---------------- problem constants ----------------
#define EPSP 5.0f
#define BNEPS 1e-5f
constexpr int B_  = 64;    // batch
constexpr int T_  = 768;   // timesteps in
constexpr int D_  = 128;   // input feature
constexpr int E_  = 64;    // embedding (conv out channels)
constexpr int H_  = 128;   // hidden
constexpr int FH_ = 512;   // 4*H
constexpr int TC_ = 256;   // conv output steps
constexpr int O_  = 10;    // output classes

// ---------------- workspace layout (floats) ----------------
constexpr size_t EMB_OFF = 0;                                   // B*TC*E   [b][tc][e]
constexpr size_t SUM_OFF = EMB_OFF + (size_t)B_ * TC_ * E_;     // 128  (sum[64], ssq[64])
constexpr size_t SCL_OFF = SUM_OFF + 128;                       // 128  (scale[64], shift[64])
constexpr size_t WT_OFF  = SCL_OFF + 128;                       // 24576: w_ih transposed [gate(i,f,g)][e][j]
constexpr size_t WIH_OFF = WT_OFF + (size_t)FH_ * H_;           // 32768  packed [e4][j][4] (zx_kernel)
constexpr size_t CWT_OFF = WIH_OFF + (size_t)FH_ * E_;          // 24576  [k][d][e]
constexpr size_t ZX_OFF  = CWT_OFF + (size_t)E_ * D_ * 3;       // B*TC*FH [b][t][j]
constexpr size_t WS_FLOATS = ZX_OFF + (size_t)B_ * TC_ * FH_;

typedef __bf16 bf16x8 __attribute__((ext_vector_type(8)));
typedef __bf16 bf16x4 __attribute__((ext_vector_type(4)));
typedef float  floatx4 __attribute__((ext_vector_type(4)));

__device__ inline float fast_rcp(float x) {
#if __has_builtin(__builtin_amdgcn_rcpf)
  return __builtin_amdgcn_rcpf(x);
#else
  return 1.0f / x;
#endif
}
__device__ inline float frsq(float x) {
#if __has_builtin(__builtin_amdgcn_rsqf)
  return __builtin_amdgcn_rsqf(x);
#else
  return rsqrtf(x);
#endif
}
__device__ inline float fexp2(float x) {
#if __has_builtin(__builtin_amdgcn_exp2f)
  return __builtin_amdgcn_exp2f(x);
#else
  return exp2f(x);
#endif
}
__device__ inline float rl(float v, int lane) {
  return __int_as_float(__builtin_amdgcn_readlane(__float_as_int(v), lane));
}
#define LOG2E 1.4426950408889634f
__device__ inline float fsigmoid(float x) {
  return fast_rcp(1.f + fexp2(-LOG2E * x));
}
__device__ inline float ftanh(float x) {
  return 1.f - 2.f * fast_rcp(1.f + fexp2(2.f * LOG2E * x));
}

// ---------------- prep: weight repack + zero BN sums ----------------
__global__ void prep_kernel(const float* __restrict__ conv_w,
                            const float* __restrict__ w_ih,
                            float* __restrict__ ws) {
  int gid = blockIdx.x * blockDim.x + threadIdx.x;
  int nthr = gridDim.x * blockDim.x;
  for (int i = gid; i < 128; i += nthr) ws[SUM_OFF + i] = 0.f;
  // w_ih [512][64] -> packed [16][512][4]  (zx_kernel)
  for (int s = gid; s < FH_ * E_; s += nthr) {
    int j = s >> 6, e = s & 63;
    ws[WIH_OFF + ((size_t)(e >> 2) * FH_ + j) * 4 + (e & 3)] = w_ih[s];
  }
  // w_ih gates i,f,g transposed: Wt[g][e][j] = w_ih[(g*128+j)*64+e]  (scan G-build)
  for (int s = gid; s < 3 * H_ * E_ * 2; s += nthr) {   // 3*64*128 = 24576
    int g = s >> 13; int r = s & 8191; int e = r >> 7; int j = r & 127;
    ws[WT_OFF + s] = w_ih[((size_t)(g * 128 + j)) * 64 + e];
  }
  // conv_w [e][d][k] -> [k][d][e]
  for (int s = gid; s < E_ * D_ * 3; s += nthr) {
    int e = s / 384; int r = s - e * 384; int d = r / 3; int k = r - d * 3;
    ws[CWT_OFF + ((size_t)k * D_ + d) * E_ + e] = conv_w[s];
  }
}

// ---------------- conv + L2-normalize + BN partial sums ----------------
__global__ __launch_bounds__(256) void conv_bn_kernel(const float* __restrict__ inputs,
                                                      const float* __restrict__ conv_b,
                                                      float* __restrict__ ws) {
  __shared__ float xin[48 * 129];
  __shared__ float rnorm[48];
  __shared__ float cwc[3 * 16 * 64];
  __shared__ float bnr1[256], bnr2[256];
  int tid = threadIdx.x;
  int bb = blockIdx.x >> 4, tcg = blockIdx.x & 15;
  const float* inp = inputs + ((size_t)bb * T_ + (size_t)tcg * 48) * D_;
  for (int idx = tid; idx < 48 * 128; idx += 256) {
    int r = idx >> 7, d = idx & 127;
    xin[r * 129 + d] = inp[idx];
  }
  __syncthreads();
  if (tid < 48) {
    float ss = 0.f;
    for (int d = 0; d < 128; ++d) { float v = xin[tid * 129 + d]; ss += v * v; }
    rnorm[tid] = 1.0f / fmaxf(sqrtf(ss), 1e-12f);
  }
  __syncthreads();
  for (int idx = tid; idx < 48 * 128; idx += 256) {
    int r = idx >> 7, d = idx & 127;
    xin[r * 129 + d] *= rnorm[r];
  }
  int e = tid & 63, tg = tid >> 6;
  float cb = conv_b[e];
  float acc[4];
#pragma unroll
  for (int q = 0; q < 4; ++q) acc[q] = cb;
  for (int ch = 0; ch < 8; ++ch) {
    __syncthreads();
    for (int idx = tid; idx < 3072; idx += 256) {
      int k = idx >> 10; int i2 = idx & 1023; int dd = i2 >> 6; int e2 = i2 & 63;
      cwc[idx] = ws[CWT_OFF + ((size_t)k * D_ + ch * 16 + dd) * E_ + e2];
    }
    __syncthreads();
    for (int dd = 0; dd < 16; ++dd) {
      int dcol = ch * 16 + dd;
#pragma unroll
      for (int k = 0; k < 3; ++k) {
        float w = cwc[(k * 16 + dd) * 64 + e];
#pragma unroll
        for (int q = 0; q < 4; ++q) {
          int tcl = tg * 4 + q;
          acc[q] += w * xin[(3 * tcl + k) * 129 + dcol];
        }
      }
    }
  }
  float ps = 0.f, pss = 0.f;
#pragma unroll
  for (int q = 0; q < 4; ++q) {
    int tcl = tg * 4 + q;
    ws[EMB_OFF + ((size_t)bb * TC_ + tcg * 16 + tcl) * E_ + e] = acc[q];
    ps += acc[q]; pss += acc[q] * acc[q];
  }
  bnr1[tg * 64 + e] = ps;
  bnr2[tg * 64 + e] = pss;
  __syncthreads();
  if (tid < 64) {
    float s1 = bnr1[tid] + bnr1[64 + tid] + bnr1[128 + tid] + bnr1[192 + tid];
    float s2 = bnr2[tid] + bnr2[64 + tid] + bnr2[128 + tid] + bnr2[192 + tid];
    atomicAdd(&ws[SUM_OFF + tid], s1);
    atomicAdd(&ws[SUM_OFF + 64 + tid], s2);
  }
}

// ---------------- BN finalize ----------------
__global__ void bn_finalize_kernel(const float* __restrict__ gamma,
                                   const float* __restrict__ beta,
                                   float* __restrict__ ws) {
  int e = threadIdx.x;
  if (e < 64) {
    const float n = (float)(B_ * TC_);
    float mean = ws[SUM_OFF + e] / n;
    float var = ws[SUM_OFF + 64 + e] / n - mean * mean;
    float sc = gamma[e] * rsqrtf(var + BNEPS);
    ws[SCL_OFF + e] = sc;
    ws[SCL_OFF + 64 + e] = beta[e] - mean * sc;
  }
}

// ---------------- z_x = relu(bn(emb)) @ w_ih^T + b_ih + b_hh ----------------
__global__ __launch_bounds__(256) void zx_kernel(const float* __restrict__ b_ih,
                                                 const float* __restrict__ b_hh,
                                                 float* __restrict__ ws) {
  __shared__ __align__(16) float actT[16 * 64];
  int tid = threadIdx.x;
  int bb = blockIdx.x >> 4, tg2 = blockIdx.x & 15;
  for (int idx = tid; idx < 1024; idx += 256) {
    int tl = idx >> 6, e2 = idx & 63;
    float v = ws[EMB_OFF + ((size_t)bb * TC_ + tg2 * 16 + tl) * E_ + e2];
    actT[idx] = fmaxf(v * ws[SCL_OFF + e2] + ws[SCL_OFF + 64 + e2], 0.f);
  }
  __syncthreads();
  int j0 = tid, j1 = tid + 256;
  float acc0[16], acc1[16];
  float bias0 = b_ih[j0] + b_hh[j0];
  float bias1 = b_ih[j1] + b_hh[j1];
#pragma unroll
  for (int tl = 0; tl < 16; ++tl) { acc0[tl] = bias0; acc1[tl] = bias1; }
  const float* wp = ws + WIH_OFF;
  for (int e4 = 0; e4 < 16; ++e4) {
    float4 w0 = *(const float4*)(wp + ((size_t)e4 * FH_ + j0) * 4);
    float4 w1 = *(const float4*)(wp + ((size_t)e4 * FH_ + j1) * 4);
#pragma unroll
    for (int tl = 0; tl < 16; ++tl) {
      float4 a4 = *(const float4*)(actT + tl * 64 + e4 * 4);
      acc0[tl] += w0.x * a4.x + w0.y * a4.y + w0.z * a4.z + w0.w * a4.w;
      acc1[tl] += w1.x * a4.x + w1.y * a4.y + w1.z * a4.z + w1.w * a4.w;
    }
  }
#pragma unroll
  for (int tl = 0; tl < 16; ++tl) {
    size_t base = ZX_OFF + ((size_t)bb * TC_ + tg2 * 16 + tl) * FH_;
    ws[base + j0] = acc0[tl];
    ws[base + j1] = acc1[tl];
  }
}

// ---------------- the sequential ProxLSTM scan: 1 block/batch, 1024 threads ----------------
// w_hh lives permanently in VGPRs as bf16 hi/lo MFMA A-fragments (64 VGPRs/thread);
// z = W_hh.h via MFMA with B = [h_hi, h_lo] (all 4 cross terms kept, rel err ~2^-18).
__global__ __launch_bounds__(1024, 1) void scan_kernel(const float* __restrict__ w_hh,
                                                       const float* __restrict__ lin_w,
                                                       const float* __restrict__ lin_b,
                                                       const float* __restrict__ ws,
                                                       float* __restrict__ out) {
  __shared__ __align__(16) __bf16 GtHi[80 * 136], GtLo[80 * 136];  // rows 0-63 = G^T[e][h], 64 = s
  __shared__ __align__(16) __bf16 BxHi[16 * 72], BxLo[16 * 72];    // row 0 = x (others garbage, unused)
  __shared__ __align__(16) __bf16 hbH[128], hbL[128];              // h split bf16
  __shared__ float M_s[64 * 65];
  __shared__ float Lp_s[16 * 64];
  __shared__ __align__(16) float z0_s[512], z1_s[512], zx_s[512];
  __shared__ __align__(16) float s_s[128], o_s[128], c_s[128], h_s[128];
  __shared__ float y_s[64];

  const int tid = threadIdx.x;
  const int bb = blockIdx.x;
  const int lane = tid & 63;
  const int wv = tid >> 6;            // 0..15
  const int m = lane & 15, q = lane >> 4;
  const int hg = tid >> 5;            // 0..31  (G-build: 4 h-rows)
  const int ep = tid & 31;            // 0..31  (G-build: 2 e-cols)
  const int h0 = hg * 4, e0 = ep * 2;

  // ---- persistent w_hh MFMA A-fragments (bf16 hi/lo), 64 VGPRs ----
  bf16x8 WH[2][4], WL[2][4];
#pragma unroll
  for (int rti = 0; rti < 2; ++rti) {
    int R = (wv * 2 + rti) * 16 + m;
#pragma unroll
    for (int kt = 0; kt < 4; ++kt) {
      const float* p = w_hh + (size_t)R * 128 + kt * 32 + q * 8;
      float4 a = *(const float4*)p;
      float4 b2 = *(const float4*)(p + 4);
      float v0[8] = {a.x, a.y, a.z, a.w, b2.x, b2.y, b2.z, b2.w};
#pragma unroll
      for (int j = 0; j < 8; ++j) {
        __bf16 hi = (__bf16)v0[j];
        WH[rti][kt][j] = hi;
        WL[rti][kt][j] = (__bf16)(v0[j] - (float)hi);
      }
    }
  }

  if (tid < 128) {
    c_s[tid] = 0.f; h_s[tid] = 0.f;
    hbH[tid] = (__bf16)0.f; hbL[tid] = (__bf16)0.f;
  }
  const float* zxp = ws + ZX_OFF + (size_t)bb * TC_ * FH_;
  const float* wt  = ws + WT_OFF;
  float zx = (tid < 512) ? zxp[tid] : 0.f;
  float dinv = 1.f;          // wave-0: 1/L[lane][lane]
  bf16x8 EH[2], EL[2];       // E-phase A-fragments (prefetched during pan-3)
  __syncthreads();

  for (int t = 0; t < TC_; ++t) {
    float4 tv[6];
    // ---- A: z = W_hh.h via MFMA (16/wave); lanes m=0/1 hold the two h-halves ----
    {
      bf16x8 Bf[4];
#pragma unroll
      for (int kt = 0; kt < 4; ++kt) {
        bf16x8 hh = *(const bf16x8*)(hbH + kt * 32 + q * 8);
        bf16x8 hl = *(const bf16x8*)(hbL + kt * 32 + q * 8);
        Bf[kt] = (m == 1) ? hl : hh;
      }
      floatx4 CA0 = {0,0,0,0}, CA1 = {0,0,0,0}, CB0 = {0,0,0,0}, CB1 = {0,0,0,0};
#pragma unroll
      for (int kt = 0; kt < 4; ++kt) {
        CA0 = __builtin_amdgcn_mfma_f32_16x16x32_bf16(WH[0][kt], Bf[kt], CA0, 0, 0, 0);
        CA1 = __builtin_amdgcn_mfma_f32_16x16x32_bf16(WH[1][kt], Bf[kt], CA1, 0, 0, 0);
        CB0 = __builtin_amdgcn_mfma_f32_16x16x32_bf16(WL[0][kt], Bf[kt], CB0, 0, 0, 0);
        CB1 = __builtin_amdgcn_mfma_f32_16x16x32_bf16(WL[1][kt], Bf[kt], CB1, 0, 0, 0);
      }
      // issue G-build weight stream (drains at this barrier, hidden behind z writes)
#pragma unroll
      for (int g = 0; g < 3; ++g)
#pragma unroll
        for (int e = 0; e < 2; ++e)
          tv[g * 2 + e] = *(const float4*)(wt + (size_t)g * 8192 + (size_t)(e0 + e) * 128 + h0);
      if (tid < 512) zx_s[tid] = zx;
      if (m == 0) {
#pragma unroll
        for (int r = 0; r < 4; ++r) {
          z0_s[(wv * 2 + 0) * 16 + q * 4 + r] = CA0[r] + CB0[r];
          z0_s[(wv * 2 + 1) * 16 + q * 4 + r] = CA1[r] + CB1[r];
        }
      } else if (m == 1) {
#pragma unroll
        for (int r = 0; r < 4; ++r) {
          z1_s[(wv * 2 + 0) * 16 + q * 4 + r] = CA0[r] + CB0[r];
          z1_s[(wv * 2 + 1) * 16 + q * 4 + r] = CA1[r] + CB1[r];
        }
      }
    }
    __syncthreads();
    // ---- G-build with fused gates (each thread: 4 h-rows x 2 e-cols) ----
    {
      float4 vi, vf, vg, vo;
      {
        float4 a0 = *(const float4*)(z0_s + h0), b0 = *(const float4*)(z1_s + h0), x0 = *(const float4*)(zx_s + h0);
        vi.x = a0.x + b0.x + x0.x; vi.y = a0.y + b0.y + x0.y; vi.z = a0.z + b0.z + x0.z; vi.w = a0.w + b0.w + x0.w;
        float4 a1 = *(const float4*)(z0_s + 128 + h0), b1 = *(const float4*)(z1_s + 128 + h0), x1 = *(const float4*)(zx_s + 128 + h0);
        vf.x = a1.x + b1.x + x1.x; vf.y = a1.y + b1.y + x1.y; vf.z = a1.z + b1.z + x1.z; vf.w = a1.w + b1.w + x1.w;
        float4 a2 = *(const float4*)(z0_s + 256 + h0), b2 = *(const float4*)(z1_s + 256 + h0), x2 = *(const float4*)(zx_s + 256 + h0);
        vg.x = a2.x + b2.x + x2.x; vg.y = a2.y + b2.y + x2.y; vg.z = a2.z + b2.z + x2.z; vg.w = a2.w + b2.w + x2.w;
        float4 a3 = *(const float4*)(z0_s + 384 + h0), b3 = *(const float4*)(z1_s + 384 + h0), x3 = *(const float4*)(zx_s + 384 + h0);
        vo.x = a3.x + b3.x + x3.x; vo.y = a3.y + b3.y + x3.y; vo.z = a3.z + b3.z + x3.z; vo.w = a3.w + b3.w + x3.w;
      }
      float4 cc = *(const float4*)(c_s + h0);
      float ziA[4] = {vi.x, vi.y, vi.z, vi.w};
      float zfA[4] = {vf.x, vf.y, vf.z, vf.w};
      float zgA[4] = {vg.x, vg.y, vg.z, vg.w};
      float zoA[4] = {vo.x, vo.y, vo.z, vo.w};
      float cA[4]  = {cc.x, cc.y, cc.z, cc.w};
      float sv[4], ov[4], A1[4], A2[4], A3[4];
#pragma unroll
      for (int r = 0; r < 4; ++r) {
        float ig = fsigmoid(ziA[r]);
        float fg = fsigmoid(zfA[r]);
        float gg = ftanh(zgA[r]);
        sv[r] = fg * cA[r] + ig * gg;
        ov[r] = fsigmoid(zoA[r]);
        A1[r] = ig * (1.f - ig) * gg;
        A2[r] = fg * (1.f - fg) * cA[r];
        A3[r] = ig * (1.f - gg * gg);
      }
      if (ep == 0) {
        *(float4*)(s_s + h0) = (float4){sv[0], sv[1], sv[2], sv[3]};
        *(float4*)(o_s + h0) = (float4){ov[0], ov[1], ov[2], ov[3]};
        bf16x4 sh, sl;
#pragma unroll
        for (int r = 0; r < 4; ++r) {
          __bf16 hi = (__bf16)sv[r];
          sh[r] = hi; sl[r] = (__bf16)(sv[r] - (float)hi);
        }
        *(bf16x4*)(GtHi + 64 * 136 + h0) = sh;
        *(bf16x4*)(GtLo + 64 * 136 + h0) = sl;
      }
      const float* tvf = (const float*)tv;   // tvf[(g*2+e)*4 + r]
#pragma unroll
      for (int e = 0; e < 2; ++e) {
        bf16x4 gh, gl;
#pragma unroll
        for (int r = 0; r < 4; ++r) {
          float gv = A1[r] * tvf[e * 4 + r] + A2[r] * tvf[8 + e * 4 + r] + A3[r] * tvf[16 + e * 4 + r];
          __bf16 hi = (__bf16)gv;
          gh[r] = hi; gl[r] = (__bf16)(gv - (float)hi);
        }
        *(bf16x4*)(GtHi + (e0 + e) * 136 + h0) = gh;
        *(bf16x4*)(GtLo + (e0 + e) * 136 + h0) = gl;
      }
      if (tid < 512 && t + 1 < TC_) zx = zxp[(size_t)(t + 1) * FH_ + tid];
    }
    __syncthreads();
    // ---- Gram via MFMA: 16 units (rt,ci<4) + 4 y-units (ci=4 on waves 12-15) ----
    {
      int rt = wv & 3, ci0 = wv >> 2;
      bf16x8 Ah[4], Al[4];
#pragma unroll
      for (int kt = 0; kt < 4; ++kt) {
        Ah[kt] = *(const bf16x8*)(GtHi + (rt * 16 + m) * 136 + kt * 32 + q * 8);
        Al[kt] = *(const bf16x8*)(GtLo + (rt * 16 + m) * 136 + kt * 32 + q * 8);
      }
#pragma unroll
      for (int un = 0; un < 2; ++un) {
        int ci = (un == 0) ? ci0 : 4;
        if (un == 1 && wv < 12) break;
        floatx4 C = {0,0,0,0};
#pragma unroll
        for (int p = 0; p < 3; ++p) {
          const __bf16* Bb = (p == 1) ? GtLo : GtHi;
#pragma unroll
          for (int kt = 0; kt < 4; ++kt) {
            bf16x8 Bf = *(const bf16x8*)(Bb + (ci * 16 + m) * 136 + kt * 32 + q * 8);
            bf16x8 Af = (p < 2) ? Ah[kt] : Al[kt];
            C = __builtin_amdgcn_mfma_f32_16x16x32_bf16(Af, Bf, C, 0, 0, 0);
          }
        }
#pragma unroll
        for (int reg = 0; reg < 4; ++reg) {
          int grow = rt * 16 + q * 4 + reg;
          if (ci < 4) {
            int gcol = ci * 16 + m;
            M_s[grow * 65 + gcol] = EPSP * C[reg] + ((grow == gcol) ? 1.f : 0.f);
          } else if (m == 0) {
            y_s[grow] = C[reg];
          }
        }
      }
    }
    __syncthreads();
    // ---- Cholesky: factor (wave 0) + trailing (16 waves); E-prefetch during pan 3 ----
#pragma unroll 1
    for (int pan = 0; pan < 4; ++pan) {
      int j0 = pan * 16;
      if (wv == 0) {
        float p[16];
#pragma unroll
        for (int jj = 0; jj < 16; ++jj) p[jj] = M_s[lane * 65 + j0 + jj];
#pragma unroll
        for (int jj = 0; jj < 16; ++jj) {
          float d  = rl(p[jj], j0 + jj);
          float rs = frsq(d);
          p[jj] *= rs;                         // diag lane: d*rs = sqrt(d)
          dinv = (lane == j0 + jj) ? rs : dinv;
#pragma unroll
          for (int kk = jj + 1; kk < 16; ++kk) {
            float l = rl(p[jj], j0 + kk);
            p[kk] -= p[jj] * l;
          }
        }
#pragma unroll
        for (int jj = 0; jj < 16; ++jj) {
          M_s[lane * 65 + j0 + jj] = p[jj];
          Lp_s[jj * 64 + lane] = p[jj];
        }
        if (pan == 3) {
          float r = y_s[lane];
          // forward: L y' = y
#pragma unroll 16
          for (int i = 0; i < 64; ++i) {
            float Lri = M_s[lane * 65 + i];
            float vv  = rl(r, i) * rl(dinv, i);
            float upd = r - Lri * vv;
            r = (lane == i) ? vv : ((lane > i) ? upd : r);
          }
          // backward: L^T x = y'
#pragma unroll 16
          for (int i = 63; i >= 0; --i) {
            float Lil = M_s[i * 65 + lane];
            float vv  = rl(r, i) * rl(dinv, i);
            float upd = r - Lil * vv;
            r = (lane == i) ? vv : ((lane < i) ? upd : r);
          }
          __bf16 xh = (__bf16)r;
          BxHi[lane] = xh;
          BxLo[lane] = (__bf16)(r - (float)xh);
        }
      } else if (pan == 3 && wv >= 8) {
        // prefetch E A-fragments (G rows rt_e*16.., transposed from Gt) while wave 0 solves
        int rte = wv - 8;
#pragma unroll
        for (int kt = 0; kt < 2; ++kt) {
#pragma unroll
          for (int j = 0; j < 8; ++j) {
            int e = kt * 32 + q * 8 + j;
            EH[kt][j] = GtHi[e * 136 + rte * 16 + m];
            EL[kt][j] = GtLo[e * 136 + rte * 16 + m];
          }
        }
      }
      __syncthreads();
      if (pan < 3) {
        float Lrow[16];
#pragma unroll
        for (int jj = 0; jj < 16; ++jj) Lrow[jj] = Lp_s[jj * 64 + lane];
        for (int k = j0 + 16 + wv; k < 64; k += 16) {
          float acc = M_s[lane * 65 + k];
#pragma unroll
          for (int jj = 0; jj < 16; ++jj) acc -= Lrow[jj] * Lp_s[jj * 64 + k];
          M_s[lane * 65 + k] = acc;
        }
        __syncthreads();
      }
    }
    // ---- E: u = G x via MFMA (waves 8-15, prefetched frags); c,h update ----
    if (wv >= 8) {
      int rte = wv - 8;
      floatx4 C = {0,0,0,0};
#pragma unroll
      for (int p = 0; p < 3; ++p) {
        const __bf16* Bb = (p == 1) ? BxLo : BxHi;
#pragma unroll
        for (int kt = 0; kt < 2; ++kt) {
          bf16x8 Bf = *(const bf16x8*)(Bb + m * 72 + kt * 32 + q * 8);
          bf16x8 Af = (p < 2) ? EH[kt] : EL[kt];
          C = __builtin_amdgcn_mfma_f32_16x16x32_bf16(Af, Bf, C, 0, 0, 0);
        }
      }
      if (m == 0) {
#pragma unroll
        for (int reg = 0; reg < 4; ++reg) {
          int grow = rte * 16 + q * 4 + reg;
          float cn = s_s[grow] - EPSP * C[reg];
          float hn = o_s[grow] * ftanh(cn);
          c_s[grow] = cn;
          h_s[grow] = hn;
          __bf16 hi = (__bf16)hn;
          hbH[grow] = hi;
          hbL[grow] = (__bf16)(hn - (float)hi);
        }
      }
    }
    __syncthreads();
  }
  // ---- head ----
  if (tid < O_) {
    float acc = lin_b[tid];
    for (int hh2 = 0; hh2 < 128; ++hh2) acc += h_s[hh2] * lin_w[tid * 128 + hh2];
    out[(size_t)bb * O_ + tid] = acc;
  }
}

// ---------------- launch ----------------
extern "C" void kernel_launch(void* const* d_in, const int* in_sizes, int n_in,
                              void* d_out, int out_size, void* d_ws, size_t ws_size,
                              hipStream_t stream) {
  (void)in_sizes; (void)n_in; (void)out_size;
  const float* inputs  = (const float*)d_in[0];
  const float* conv_w  = (const float*)d_in[2];
  const float* conv_b  = (const float*)d_in[3];
  const float* gamma   = (const float*)d_in[4];
  const float* beta    = (const float*)d_in[5];
  const float* w_ih    = (const float*)d_in[6];
  const float* w_hh    = (const float*)d_in[7];
  const float* b_ih    = (const float*)d_in[8];
  const float* b_hh    = (const float*)d_in[9];
  const float* lin_w   = (const float*)d_in[10];
  const float* lin_b   = (const float*)d_in[11];
  float* out = (float*)d_out;
  float* ws  = (float*)d_ws;

  if (ws_size < WS_FLOATS * sizeof(float)) return;

  hipLaunchKernelGGL(prep_kernel, dim3(192), dim3(256), 0, stream, conv_w, w_ih, ws);
  hipLaunchKernelGGL(conv_bn_kernel, dim3(1024), dim3(256), 0, stream, inputs, conv_b, ws);
  hipLaunchKernelGGL(bn_finalize_kernel, dim3(1), dim3(64), 0, stream, gamma, beta, ws);
  hipLaunchKernelGGL(zx_kernel, dim3(1024), dim3(256), 0, stream, b_ih, b_hh, ws);
  hipLaunchKernelGGL(scan_kernel, dim3(64), dim3(1024), 0, stream, w_hh, lin_w, lin_b, ws, out);
}